// Round 3
// baseline (119.129 us; speedup 1.0000x reference)
//
#include <hip/hip_runtime.h>
#include <stdint.h>

#define NN 4096
#define DD 512
#define NH 3
#define MAXDEG 256   // mean degree ~41, sd ~6.4; 256 is >30 sigma headroom

typedef float f4v __attribute__((ext_vector_type(4)));

__device__ __forceinline__ unsigned short f2bf_rn(float x) {
    union { float f; uint32_t u; } v; v.f = x;
    uint32_t u = v.u;
    uint32_t r = (u + 0x7FFFu + ((u >> 16) & 1u)) >> 16;
    return (unsigned short)r;
}
__device__ __forceinline__ float bflo(uint32_t u) {
    union { uint32_t u; float f; } v; v.u = u << 16; return v.f;
}
__device__ __forceinline__ float bfhi(uint32_t u) {
    union { uint32_t u; float f; } v; v.u = u & 0xFFFF0000u; return v.f;
}

// Kernel A: one wave per node j. Computes w[j][h] = exp(relu(h[j]·P[:,h]))
// and writes a round-to-nearest bf16 copy of h[j,:] (halves gather traffic,
// keeps the gather table at 4MB so it caches in per-XCD L2).
__global__ __launch_bounds__(256) void prep_kernel(
    const float* __restrict__ h, const float* __restrict__ P,
    float* __restrict__ w, unsigned short* __restrict__ hb)
{
    int gid = blockIdx.x * 256 + threadIdx.x;
    int row = gid >> 6, ln = gid & 63;
    const f4v* h4 = (const f4v*)(h + (size_t)row * DD);
    // h fp32 is never read again -> stream it
    f4v va = __builtin_nontemporal_load(&h4[ln * 2]);
    f4v vb = __builtin_nontemporal_load(&h4[ln * 2 + 1]);
    float e[8] = { va[0], va[1], va[2], va[3], vb[0], vb[1], vb[2], vb[3] };

    // pack 8 bf16 -> 16B coalesced store
    uint32_t pk0 = (uint32_t)f2bf_rn(e[0]) | ((uint32_t)f2bf_rn(e[1]) << 16);
    uint32_t pk1 = (uint32_t)f2bf_rn(e[2]) | ((uint32_t)f2bf_rn(e[3]) << 16);
    uint32_t pk2 = (uint32_t)f2bf_rn(e[4]) | ((uint32_t)f2bf_rn(e[5]) << 16);
    uint32_t pk3 = (uint32_t)f2bf_rn(e[6]) | ((uint32_t)f2bf_rn(e[7]) << 16);
    uint4 pk = make_uint4(pk0, pk1, pk2, pk3);
    *(uint4*)(hb + (size_t)row * DD + ln * 8) = pk;

    // partial dots (lane covers d = ln*8..ln*8+7; P is 6KB, L1-resident)
    int d0 = ln * 8;
    float a0 = 0.f, a1 = 0.f, a2 = 0.f;
    #pragma unroll
    for (int k = 0; k < 8; ++k) {
        float hv = e[k];
        const float* Pr = P + (size_t)(d0 + k) * NH;
        a0 = fmaf(hv, Pr[0], a0);
        a1 = fmaf(hv, Pr[1], a1);
        a2 = fmaf(hv, Pr[2], a2);
    }
    #pragma unroll
    for (int off = 32; off > 0; off >>= 1) {
        a0 += __shfl_down(a0, off);
        a1 += __shfl_down(a1, off);
        a2 += __shfl_down(a2, off);
    }
    if (ln == 0) {
        w[row * NH + 0] = expf(fmaxf(a0, 0.f));
        w[row * NH + 1] = expf(fmaxf(a1, 0.f));
        w[row * NH + 2] = expf(fmaxf(a2, 0.f));
    }
}

// Kernel B: one wave per output row (4 independent waves/block, no barriers).
// Phase 1: issue ALL 16 graph-row loads up front (16KB/wave in flight, no
//          branches between loads -> compiler clusters them; processing
//          pipelines against vmcnt count-down), then ballot-compact.
// Phase 2: Z + combined coefficients.
// Phase 3: gather, 8 neighbor rows in flight per iteration.
__global__ __launch_bounds__(256) void att_agg_kernel(
    const float* __restrict__ g, const unsigned short* __restrict__ hb,
    const float* __restrict__ w, float* __restrict__ out)
{
    __shared__ int   s_idx[4][MAXDEG + 8];
    __shared__ float s_c[4][MAXDEG + 8];

    const int wv = threadIdx.x >> 6, ln = threadIdx.x & 63;
    const int row = blockIdx.x * 4 + wv;
    int*   __restrict__ idxb = s_idx[wv];
    float* __restrict__ cb   = s_c[wv];

    // ---- Phase 1: load entire 16KB graph row up front, then compact ----
    const f4v* g4 = (const f4v*)(g + (size_t)row * NN);
    f4v v[16];
    #pragma unroll
    for (int u = 0; u < 16; ++u)
        v[u] = __builtin_nontemporal_load(&g4[u * 64 + ln]);   // stream

    int cnt = 0;   // wave-uniform (ballot/popc) -> SGPR
    #pragma unroll
    for (int u = 0; u < 16; ++u) {
        int base = (u * 64 + ln) * 4;
        #pragma unroll
        for (int k = 0; k < 4; ++k) {
            bool p = v[u][k] > 0.f;
            unsigned long long m = __ballot(p);
            if (m) {   // wave-uniform
                if (p) {
                    unsigned pre = __builtin_amdgcn_mbcnt_lo((unsigned)m, 0u);
                    pre = __builtin_amdgcn_mbcnt_hi((unsigned)(m >> 32), pre);
                    int pos = cnt + (int)pre;
                    if (pos < MAXDEG) idxb[pos] = base + k;
                }
                cnt += __popcll(m);
            }
        }
    }
    int nnz = cnt > MAXDEG ? MAXDEG : cnt;

    float* orow = out + (size_t)row * DD + ln * 8;
    if (nnz == 0) {   // zero-degree row: rowsum=0 => output 0 (wave-uniform)
        f4v z = {0.f, 0.f, 0.f, 0.f};
        __builtin_nontemporal_store(z, (f4v*)orow);
        __builtin_nontemporal_store(z, (f4v*)(orow + 4));
        return;
    }

    __builtin_amdgcn_wave_barrier();   // fence: LDS writes before reads

    // ---- Phase 2a: Z over compacted list ----
    float z0 = 0.f, z1 = 0.f, z2 = 0.f;
    for (int t = ln; t < nnz; t += 64) {
        int j = idxb[t];
        const float* wr = w + (size_t)j * NH;
        z0 += wr[0]; z1 += wr[1]; z2 += wr[2];
    }
    #pragma unroll
    for (int off = 32; off > 0; off >>= 1) {
        z0 += __shfl_xor(z0, off);
        z1 += __shfl_xor(z1, off);
        z2 += __shfl_xor(z2, off);
    }
    float RS = (float)nnz;   // binary graph: rowsum == degree
    float sc0 = RS / z0, sc1 = RS / z1, sc2 = RS / z2;

    // ---- Phase 2b: per-neighbor combined coefficient (+ pad to x8) ----
    int npad = (nnz + 7) & ~7;
    for (int t = ln; t < npad; t += 64) {
        if (t < nnz) {
            int j = idxb[t];
            const float* wr = w + (size_t)j * NH;   // L1-hit (just loaded)
            cb[t] = fmaf(sc0, wr[0], fmaf(sc1, wr[1], sc2 * wr[2]));
        } else {
            idxb[t] = idxb[0];
            cb[t] = 0.f;
        }
    }
    __builtin_amdgcn_wave_barrier();

    // ---- Phase 3: out[row,:] = sum_t c_t * hb[j_t,:]  (8 rows in flight) ----
    const unsigned short* hcol = hb + ln * 8;
    float acc0=0.f,acc1=0.f,acc2=0.f,acc3=0.f,acc4=0.f,acc5=0.f,acc6=0.f,acc7=0.f;
    for (int t = 0; t < npad; t += 8) {
        uint4 r0 = *(const uint4*)(hcol + (size_t)idxb[t+0] * DD);
        uint4 r1 = *(const uint4*)(hcol + (size_t)idxb[t+1] * DD);
        uint4 r2 = *(const uint4*)(hcol + (size_t)idxb[t+2] * DD);
        uint4 r3 = *(const uint4*)(hcol + (size_t)idxb[t+3] * DD);
        uint4 r4 = *(const uint4*)(hcol + (size_t)idxb[t+4] * DD);
        uint4 r5 = *(const uint4*)(hcol + (size_t)idxb[t+5] * DD);
        uint4 r6 = *(const uint4*)(hcol + (size_t)idxb[t+6] * DD);
        uint4 r7 = *(const uint4*)(hcol + (size_t)idxb[t+7] * DD);
        float c0 = cb[t+0], c1 = cb[t+1], c2 = cb[t+2], c3 = cb[t+3];
        float c4 = cb[t+4], c5 = cb[t+5], c6 = cb[t+6], c7 = cb[t+7];
        acc0 = fmaf(c0, bflo(r0.x), acc0); acc1 = fmaf(c0, bfhi(r0.x), acc1);
        acc2 = fmaf(c0, bflo(r0.y), acc2); acc3 = fmaf(c0, bfhi(r0.y), acc3);
        acc4 = fmaf(c0, bflo(r0.z), acc4); acc5 = fmaf(c0, bfhi(r0.z), acc5);
        acc6 = fmaf(c0, bflo(r0.w), acc6); acc7 = fmaf(c0, bfhi(r0.w), acc7);
        acc0 = fmaf(c1, bflo(r1.x), acc0); acc1 = fmaf(c1, bfhi(r1.x), acc1);
        acc2 = fmaf(c1, bflo(r1.y), acc2); acc3 = fmaf(c1, bfhi(r1.y), acc3);
        acc4 = fmaf(c1, bflo(r1.z), acc4); acc5 = fmaf(c1, bfhi(r1.z), acc5);
        acc6 = fmaf(c1, bflo(r1.w), acc6); acc7 = fmaf(c1, bfhi(r1.w), acc7);
        acc0 = fmaf(c2, bflo(r2.x), acc0); acc1 = fmaf(c2, bfhi(r2.x), acc1);
        acc2 = fmaf(c2, bflo(r2.y), acc2); acc3 = fmaf(c2, bfhi(r2.y), acc3);
        acc4 = fmaf(c2, bflo(r2.z), acc4); acc5 = fmaf(c2, bfhi(r2.z), acc5);
        acc6 = fmaf(c2, bflo(r2.w), acc6); acc7 = fmaf(c2, bfhi(r2.w), acc7);
        acc0 = fmaf(c3, bflo(r3.x), acc0); acc1 = fmaf(c3, bfhi(r3.x), acc1);
        acc2 = fmaf(c3, bflo(r3.y), acc2); acc3 = fmaf(c3, bfhi(r3.y), acc3);
        acc4 = fmaf(c3, bflo(r3.z), acc4); acc5 = fmaf(c3, bfhi(r3.z), acc5);
        acc6 = fmaf(c3, bflo(r3.w), acc6); acc7 = fmaf(c3, bfhi(r3.w), acc7);
        acc0 = fmaf(c4, bflo(r4.x), acc0); acc1 = fmaf(c4, bfhi(r4.x), acc1);
        acc2 = fmaf(c4, bflo(r4.y), acc2); acc3 = fmaf(c4, bfhi(r4.y), acc3);
        acc4 = fmaf(c4, bflo(r4.z), acc4); acc5 = fmaf(c4, bfhi(r4.z), acc5);
        acc6 = fmaf(c4, bflo(r4.w), acc6); acc7 = fmaf(c4, bfhi(r4.w), acc7);
        acc0 = fmaf(c5, bflo(r5.x), acc0); acc1 = fmaf(c5, bfhi(r5.x), acc1);
        acc2 = fmaf(c5, bflo(r5.y), acc2); acc3 = fmaf(c5, bfhi(r5.y), acc3);
        acc4 = fmaf(c5, bflo(r5.z), acc4); acc5 = fmaf(c5, bfhi(r5.z), acc5);
        acc6 = fmaf(c5, bflo(r5.w), acc6); acc7 = fmaf(c5, bfhi(r5.w), acc7);
        acc0 = fmaf(c6, bflo(r6.x), acc0); acc1 = fmaf(c6, bfhi(r6.x), acc1);
        acc2 = fmaf(c6, bflo(r6.y), acc2); acc3 = fmaf(c6, bfhi(r6.y), acc3);
        acc4 = fmaf(c6, bflo(r6.z), acc4); acc5 = fmaf(c6, bfhi(r6.z), acc5);
        acc6 = fmaf(c6, bflo(r6.w), acc6); acc7 = fmaf(c6, bfhi(r6.w), acc7);
        acc0 = fmaf(c7, bflo(r7.x), acc0); acc1 = fmaf(c7, bfhi(r7.x), acc1);
        acc2 = fmaf(c7, bflo(r7.y), acc2); acc3 = fmaf(c7, bfhi(r7.y), acc3);
        acc4 = fmaf(c7, bflo(r7.z), acc4); acc5 = fmaf(c7, bfhi(r7.z), acc5);
        acc6 = fmaf(c7, bflo(r7.w), acc6); acc7 = fmaf(c7, bfhi(r7.w), acc7);
    }

    f4v o0 = {acc0, acc1, acc2, acc3};
    f4v o1 = {acc4, acc5, acc6, acc7};
    __builtin_nontemporal_store(o0, (f4v*)orow);
    __builtin_nontemporal_store(o1, (f4v*)(orow + 4));
}

extern "C" void kernel_launch(void* const* d_in, const int* in_sizes, int n_in,
                              void* d_out, int out_size, void* d_ws, size_t ws_size,
                              hipStream_t stream) {
    const float* g = (const float*)d_in[0];   // graph_info [N,N]
    const float* h = (const float*)d_in[1];   // h [N,D]
    const float* P = (const float*)d_in[2];   // P [D,H]
    float* out = (float*)d_out;               // [N,D] fp32

    // ws layout: w fp32 [N,3] at 0 (48 KB); bf16 h copy [N,D] at 64 KB (4 MB)
    float* w = (float*)d_ws;
    unsigned short* hb = (unsigned short*)((char*)d_ws + 65536);

    prep_kernel<<<(NN * 64) / 256, 256, 0, stream>>>(h, P, w, hb);
    att_agg_kernel<<<NN / 4, 256, 0, stream>>>(g, hb, w, out);
}

// Round 4
// 118.793 us; speedup vs baseline: 1.0028x; 1.0028x over previous
//
#include <hip/hip_runtime.h>
#include <stdint.h>

#define NN 4096
#define DD 512
#define NH 3
#define SEGCAP 80            // per-wave quarter-row nnz cap (mean 10.2, sd 3.2 -> 21 sigma)
#define MAXDEG (4 * SEGCAP)  // 320 per row

typedef float f4v __attribute__((ext_vector_type(4)));
typedef float f2v __attribute__((ext_vector_type(2)));

__device__ __forceinline__ unsigned short f2bf_rn(float x) {
    union { float f; uint32_t u; } v; v.f = x;
    uint32_t u = v.u;
    uint32_t r = (u + 0x7FFFu + ((u >> 16) & 1u)) >> 16;
    return (unsigned short)r;
}
__device__ __forceinline__ float bflo(uint32_t u) {
    union { uint32_t u; float f; } v; v.u = u << 16; return v.f;
}
__device__ __forceinline__ float bfhi(uint32_t u) {
    union { uint32_t u; float f; } v; v.u = u & 0xFFFF0000u; return v.f;
}

// Kernel A (unchanged, verified): one wave per node j.
// w[j][h] = exp(relu(h[j]·P[:,h])); hb = bf16 copy of h (halves gather bytes).
__global__ __launch_bounds__(256) void prep_kernel(
    const float* __restrict__ h, const float* __restrict__ P,
    float* __restrict__ w, unsigned short* __restrict__ hb)
{
    int gid = blockIdx.x * 256 + threadIdx.x;
    int row = gid >> 6, ln = gid & 63;
    const f4v* h4 = (const f4v*)(h + (size_t)row * DD);
    f4v va = __builtin_nontemporal_load(&h4[ln * 2]);
    f4v vb = __builtin_nontemporal_load(&h4[ln * 2 + 1]);
    float e[8] = { va[0], va[1], va[2], va[3], vb[0], vb[1], vb[2], vb[3] };

    uint32_t pk0 = (uint32_t)f2bf_rn(e[0]) | ((uint32_t)f2bf_rn(e[1]) << 16);
    uint32_t pk1 = (uint32_t)f2bf_rn(e[2]) | ((uint32_t)f2bf_rn(e[3]) << 16);
    uint32_t pk2 = (uint32_t)f2bf_rn(e[4]) | ((uint32_t)f2bf_rn(e[5]) << 16);
    uint32_t pk3 = (uint32_t)f2bf_rn(e[6]) | ((uint32_t)f2bf_rn(e[7]) << 16);
    uint4 pk = make_uint4(pk0, pk1, pk2, pk3);
    *(uint4*)(hb + (size_t)row * DD + ln * 8) = pk;

    int d0 = ln * 8;
    float a0 = 0.f, a1 = 0.f, a2 = 0.f;
    #pragma unroll
    for (int k = 0; k < 8; ++k) {
        float hv = e[k];
        const float* Pr = P + (size_t)(d0 + k) * NH;
        a0 = fmaf(hv, Pr[0], a0);
        a1 = fmaf(hv, Pr[1], a1);
        a2 = fmaf(hv, Pr[2], a2);
    }
    #pragma unroll
    for (int off = 32; off > 0; off >>= 1) {
        a0 += __shfl_down(a0, off);
        a1 += __shfl_down(a1, off);
        a2 += __shfl_down(a2, off);
    }
    if (ln == 0) {
        w[row * NH + 0] = expf(fmaxf(a0, 0.f));
        w[row * NH + 1] = expf(fmaxf(a1, 0.f));
        w[row * NH + 2] = expf(fmaxf(a2, 0.f));
    }
}

// Kernel B: one BLOCK per row (4096 blocks -> up to 8 blocks/CU = 32 waves/CU).
// Wave wv: scans graph-row quarter [wv*1024, wv*1024+1024) into a PRIVATE
// segment (no LDS atomics); Z over own segment; flat-compacts during the
// coefficient pass (prefix over 4 counts is free). Gather splits by d:
// wave wv owns d in [wv*128, wv*128+128) -> no cross-wave combine, no s_part.
__global__ __launch_bounds__(256, 8) void att_agg_kernel(
    const float* __restrict__ g, const unsigned short* __restrict__ hb,
    const float* __restrict__ w, float* __restrict__ out)
{
    __shared__ int   s_seg[4][SEGCAP];
    __shared__ int2  s_f[MAXDEG + 8];    // .x = col idx, .y = coeff (float bits)
    __shared__ int   s_cnt[4];
    __shared__ float s_z[4][3];

    const int wv = threadIdx.x >> 6, ln = threadIdx.x & 63;
    const int row = blockIdx.x;

    // ---- Phase 1: scan own 4KB quarter, hoisted loads, private compact ----
    const f4v* g4 = (const f4v*)(g + (size_t)row * NN + wv * 1024);
    f4v v0 = __builtin_nontemporal_load(&g4[0 * 64 + ln]);
    f4v v1 = __builtin_nontemporal_load(&g4[1 * 64 + ln]);
    f4v v2 = __builtin_nontemporal_load(&g4[2 * 64 + ln]);
    f4v v3 = __builtin_nontemporal_load(&g4[3 * 64 + ln]);

    int cnt = 0;   // wave-private running count -> SGPR, no atomics
    #define SCAN4(VV, U)                                                     \
    {                                                                        \
        int base = wv * 1024 + ((U) * 64 + ln) * 4;                          \
        _Pragma("unroll")                                                    \
        for (int k = 0; k < 4; ++k) {                                        \
            bool p = (VV)[k] > 0.f;                                          \
            unsigned long long m = __ballot(p);                              \
            if (m) {                                                         \
                if (p) {                                                     \
                    unsigned pre = __builtin_amdgcn_mbcnt_lo((unsigned)m, 0u); \
                    pre = __builtin_amdgcn_mbcnt_hi((unsigned)(m >> 32), pre); \
                    int pos = cnt + (int)pre;                                \
                    if (pos < SEGCAP) s_seg[wv][pos] = base + k;             \
                }                                                            \
                cnt += __popcll(m);                                          \
            }                                                                \
        }                                                                    \
    }
    SCAN4(v0, 0) SCAN4(v1, 1) SCAN4(v2, 2) SCAN4(v3, 3)
    #undef SCAN4
    if (cnt > SEGCAP) cnt = SEGCAP;
    if (ln == 0) s_cnt[wv] = cnt;
    __syncthreads();

    const int c0n = s_cnt[0], c1n = s_cnt[1], c2n = s_cnt[2], c3n = s_cnt[3];
    const int nnz = c0n + c1n + c2n + c3n;
    float* oq = out + (size_t)row * DD + wv * 128 + ln * 2;

    if (nnz == 0) {   // rowsum = 0 => output 0 (block-uniform)
        f2v z = {0.f, 0.f};
        __builtin_nontemporal_store(z, (f2v*)oq);
        return;
    }

    // ---- Phase 2: per-wave Z over own segment (w cached in regs) ----
    float z0 = 0.f, z1 = 0.f, z2 = 0.f;
    int myj = 0; float w0 = 0.f, w1 = 0.f, w2 = 0.f;
    if (ln < cnt) {
        myj = s_seg[wv][ln];
        const float* wr = w + (size_t)myj * NH;
        w0 = wr[0]; w1 = wr[1]; w2 = wr[2];
        z0 = w0; z1 = w1; z2 = w2;
    }
    for (int t = 64 + ln; t < cnt; t += 64) {   // dead in practice (cnt<=80)
        int j = s_seg[wv][t];
        const float* wr = w + (size_t)j * NH;
        z0 += wr[0]; z1 += wr[1]; z2 += wr[2];
    }
    #pragma unroll
    for (int off = 32; off > 0; off >>= 1) {
        z0 += __shfl_xor(z0, off);
        z1 += __shfl_xor(z1, off);
        z2 += __shfl_xor(z2, off);
    }
    if (ln == 0) { s_z[wv][0] = z0; s_z[wv][1] = z1; s_z[wv][2] = z2; }
    __syncthreads();

    const float Z0 = s_z[0][0] + s_z[1][0] + s_z[2][0] + s_z[3][0];
    const float Z1 = s_z[0][1] + s_z[1][1] + s_z[2][1] + s_z[3][1];
    const float Z2 = s_z[0][2] + s_z[1][2] + s_z[2][2] + s_z[3][2];
    const float RS = (float)nnz;   // binary graph: rowsum == degree
    const float sc0 = RS / Z0, sc1 = RS / Z1, sc2 = RS / Z2;

    // ---- Phase 3: coeff + flat compaction (prefix over 4 counts) ----
    const int off0 = (wv > 0 ? c0n : 0) + (wv > 1 ? c1n : 0) + (wv > 2 ? c2n : 0);
    if (ln < cnt) {
        float c = fmaf(sc0, w0, fmaf(sc1, w1, sc2 * w2));
        s_f[off0 + ln] = make_int2(myj, __float_as_int(c));
    }
    for (int t = 64 + ln; t < cnt; t += 64) {   // dead in practice
        int j = s_seg[wv][t];
        const float* wr = w + (size_t)j * NH;
        float c = fmaf(sc0, wr[0], fmaf(sc1, wr[1], sc2 * wr[2]));
        s_f[off0 + t] = make_int2(j, __float_as_int(c));
    }
    const int npad = (nnz + 7) & ~7;
    if (wv == 0) {   // pad with (col 0, coeff 0): hb[0] is valid, contributes 0
        for (int t = nnz + ln; t < npad; t += 64)
            s_f[t] = make_int2(0, 0);
    }
    __syncthreads();

    // ---- Phase 4: gather split by d. Wave wv owns d in [wv*128, wv*128+128);
    //      lane loads one dword (2 bf16) per neighbor row. 8 rows in flight. ----
    const unsigned short* hq = hb + wv * 128 + ln * 2;
    float a0 = 0.f, a1 = 0.f;
    for (int t = 0; t < npad; t += 8) {
        int2 f0 = s_f[t + 0], f1 = s_f[t + 1], f2 = s_f[t + 2], f3 = s_f[t + 3];
        int2 f4 = s_f[t + 4], f5 = s_f[t + 5], f6 = s_f[t + 6], f7 = s_f[t + 7];
        uint32_t r0 = *(const uint32_t*)(hq + (size_t)f0.x * DD);
        uint32_t r1 = *(const uint32_t*)(hq + (size_t)f1.x * DD);
        uint32_t r2 = *(const uint32_t*)(hq + (size_t)f2.x * DD);
        uint32_t r3 = *(const uint32_t*)(hq + (size_t)f3.x * DD);
        uint32_t r4 = *(const uint32_t*)(hq + (size_t)f4.x * DD);
        uint32_t r5 = *(const uint32_t*)(hq + (size_t)f5.x * DD);
        uint32_t r6 = *(const uint32_t*)(hq + (size_t)f6.x * DD);
        uint32_t r7 = *(const uint32_t*)(hq + (size_t)f7.x * DD);
        float c0 = __int_as_float(f0.y), c1 = __int_as_float(f1.y);
        float c2 = __int_as_float(f2.y), c3 = __int_as_float(f3.y);
        float c4 = __int_as_float(f4.y), c5 = __int_as_float(f5.y);
        float c6 = __int_as_float(f6.y), c7 = __int_as_float(f7.y);
        a0 = fmaf(c0, bflo(r0), a0); a1 = fmaf(c0, bfhi(r0), a1);
        a0 = fmaf(c1, bflo(r1), a0); a1 = fmaf(c1, bfhi(r1), a1);
        a0 = fmaf(c2, bflo(r2), a0); a1 = fmaf(c2, bfhi(r2), a1);
        a0 = fmaf(c3, bflo(r3), a0); a1 = fmaf(c3, bfhi(r3), a1);
        a0 = fmaf(c4, bflo(r4), a0); a1 = fmaf(c4, bfhi(r4), a1);
        a0 = fmaf(c5, bflo(r5), a0); a1 = fmaf(c5, bfhi(r5), a1);
        a0 = fmaf(c6, bflo(r6), a0); a1 = fmaf(c6, bfhi(r6), a1);
        a0 = fmaf(c7, bflo(r7), a0); a1 = fmaf(c7, bfhi(r7), a1);
    }

    f2v o = {a0, a1};
    __builtin_nontemporal_store(o, (f2v*)oq);
}

extern "C" void kernel_launch(void* const* d_in, const int* in_sizes, int n_in,
                              void* d_out, int out_size, void* d_ws, size_t ws_size,
                              hipStream_t stream) {
    const float* g = (const float*)d_in[0];   // graph_info [N,N]
    const float* h = (const float*)d_in[1];   // h [N,D]
    const float* P = (const float*)d_in[2];   // P [D,H]
    float* out = (float*)d_out;               // [N,D] fp32

    // ws layout: w fp32 [N,3] at 0 (48 KB); bf16 h copy [N,D] at 64 KB (4 MB)
    float* w = (float*)d_ws;
    unsigned short* hb = (unsigned short*)((char*)d_ws + 65536);

    prep_kernel<<<(NN * 64) / 256, 256, 0, stream>>>(h, P, w, hb);
    att_agg_kernel<<<NN, 256, 0, stream>>>(g, hb, w, out);
}

// Round 5
// 113.368 us; speedup vs baseline: 1.0508x; 1.0479x over previous
//
#include <hip/hip_runtime.h>
#include <stdint.h>

#define NN 4096
#define DD 512
#define NH 3
#define MAXDEG 256   // mean degree ~41, sd ~6.4; 256 is >30 sigma headroom

__device__ __forceinline__ unsigned short f2bf_rn(float x) {
    union { float f; uint32_t u; } v; v.f = x;
    uint32_t u = v.u;
    uint32_t r = (u + 0x7FFFu + ((u >> 16) & 1u)) >> 16;
    return (unsigned short)r;
}
__device__ __forceinline__ float bflo(uint32_t u) {
    union { uint32_t u; float f; } v; v.u = u << 16; return v.f;
}
__device__ __forceinline__ float bfhi(uint32_t u) {
    union { uint32_t u; float f; } v; v.u = u & 0xFFFF0000u; return v.f;
}

// Kernel A: one wave per node j. Computes w[j][h] = exp(relu(h[j]·P[:,h]))
// and writes a round-to-nearest bf16 copy of h[j,:] (halves gather traffic,
// makes h fit in per-XCD 4MB L2).
__global__ __launch_bounds__(256) void prep_kernel(
    const float* __restrict__ h, const float* __restrict__ P,
    float* __restrict__ w, unsigned short* __restrict__ hb)
{
    int gid = blockIdx.x * 256 + threadIdx.x;
    int row = gid >> 6, ln = gid & 63;
    const float4* h4 = (const float4*)(h + (size_t)row * DD);
    float4 va = h4[ln * 2], vb = h4[ln * 2 + 1];
    float e[8] = { va.x, va.y, va.z, va.w, vb.x, vb.y, vb.z, vb.w };

    // pack 8 bf16 -> 16B coalesced store
    uint32_t pk0 = (uint32_t)f2bf_rn(e[0]) | ((uint32_t)f2bf_rn(e[1]) << 16);
    uint32_t pk1 = (uint32_t)f2bf_rn(e[2]) | ((uint32_t)f2bf_rn(e[3]) << 16);
    uint32_t pk2 = (uint32_t)f2bf_rn(e[4]) | ((uint32_t)f2bf_rn(e[5]) << 16);
    uint32_t pk3 = (uint32_t)f2bf_rn(e[6]) | ((uint32_t)f2bf_rn(e[7]) << 16);
    uint4 pk = make_uint4(pk0, pk1, pk2, pk3);
    *(uint4*)(hb + (size_t)row * DD + ln * 8) = pk;

    // partial dots (each lane covers d = ln*8 .. ln*8+7; P is 6KB, L1-resident)
    int d0 = ln * 8;
    float a0 = 0.f, a1 = 0.f, a2 = 0.f;
    #pragma unroll
    for (int k = 0; k < 8; ++k) {
        float hv = e[k];
        const float* Pr = P + (size_t)(d0 + k) * NH;
        a0 = fmaf(hv, Pr[0], a0);
        a1 = fmaf(hv, Pr[1], a1);
        a2 = fmaf(hv, Pr[2], a2);
    }
    #pragma unroll
    for (int off = 32; off > 0; off >>= 1) {
        a0 += __shfl_down(a0, off);
        a1 += __shfl_down(a1, off);
        a2 += __shfl_down(a2, off);
    }
    if (ln == 0) {
        w[row * NH + 0] = expf(fmaxf(a0, 0.f));
        w[row * NH + 1] = expf(fmaxf(a1, 0.f));
        w[row * NH + 2] = expf(fmaxf(a2, 0.f));
    }
}

// Kernel B: one block (4 waves) per output row i.
// Phase 1: ballot-compact nonzero columns into LDS (1 atomic per wave per chunk).
// Phase 1.5: coalesced pass over compacted list -> Z[3]; rowsum == nnz (binary graph).
// Phase 2: 4 nonzeros per iteration, one dwordx4 (8 bf16) per lane, fully coalesced.
__global__ __launch_bounds__(256) void att_agg_kernel(
    const float* __restrict__ g, const unsigned short* __restrict__ hb,
    const float* __restrict__ w, float* __restrict__ out)
{
    __shared__ int   s_idx[MAXDEG + 4];
    __shared__ float s_c[MAXDEG + 4];
    __shared__ int   s_cnt;
    __shared__ float s_z[4][3];
    __shared__ float s_part[4][DD];   // 8 KB cross-wave partials

    const int row = blockIdx.x, tid = threadIdx.x;
    const int wv = tid >> 6, ln = tid & 63;
    if (tid == 0) s_cnt = 0;
    __syncthreads();

    // ---- Phase 1: scan 16KB graph row, compact nonzero columns ----
    const float4* g4 = (const float4*)(g + (size_t)row * NN);
    #pragma unroll
    for (int it = 0; it < (NN / 4) / 256; ++it) {   // 4 iterations
        int c4 = it * 256 + tid;
        float4 v = g4[c4];
        float comp[4] = { v.x, v.y, v.z, v.w };
        int base = c4 * 4;
        #pragma unroll
        for (int k = 0; k < 4; ++k) {
            bool p = comp[k] > 0.f;
            unsigned long long m = __ballot(p);
            if (m) {   // wave-uniform
                int nset = __popcll(m);
                int bpos;
                if (ln == 0) bpos = atomicAdd(&s_cnt, nset);
                bpos = __shfl(bpos, 0);
                if (p) {
                    unsigned pre = __builtin_amdgcn_mbcnt_lo((unsigned)m, 0u);
                    pre = __builtin_amdgcn_mbcnt_hi((unsigned)(m >> 32), pre);
                    int pos = bpos + (int)pre;
                    if (pos < MAXDEG) s_idx[pos] = base + k;
                }
            }
        }
    }
    __syncthreads();
    int nnz = s_cnt; if (nnz > MAXDEG) nnz = MAXDEG;

    if (nnz == 0) {   // zero-degree row: rowsum=0 => output 0 (block-uniform)
        ((float2*)(out + (size_t)row * DD))[tid] = make_float2(0.f, 0.f);
        return;
    }

    // ---- Phase 1.5: Z over compacted list (nnz <= 256 => one entry/thread) ----
    float z0 = 0.f, z1 = 0.f, z2 = 0.f, w0 = 0.f, w1 = 0.f, w2 = 0.f;
    int myj = 0;
    if (tid < nnz) {
        myj = s_idx[tid];
        const float* wr = w + (size_t)myj * NH;
        w0 = wr[0]; w1 = wr[1]; w2 = wr[2];
        z0 = w0; z1 = w1; z2 = w2;
    }
    #pragma unroll
    for (int off = 32; off > 0; off >>= 1) {
        z0 += __shfl_down(z0, off);
        z1 += __shfl_down(z1, off);
        z2 += __shfl_down(z2, off);
    }
    if (ln == 0) { s_z[wv][0] = z0; s_z[wv][1] = z1; s_z[wv][2] = z2; }
    __syncthreads();
    float Z0 = s_z[0][0] + s_z[1][0] + s_z[2][0] + s_z[3][0];
    float Z1 = s_z[0][1] + s_z[1][1] + s_z[2][1] + s_z[3][1];
    float Z2 = s_z[0][2] + s_z[1][2] + s_z[2][2] + s_z[3][2];
    float RS = (float)nnz;   // binary graph: rowsum == degree
    float sc0 = RS / Z0, sc1 = RS / Z1, sc2 = RS / Z2;

    int npad = (nnz + 3) & ~3;
    if (tid < nnz) s_c[tid] = fmaf(sc0, w0, fmaf(sc1, w1, sc2 * w2));
    else if (tid < npad) { s_idx[tid] = 0; s_c[tid] = 0.f; }
    __syncthreads();

    // ---- Phase 2: out[row,:] = sum_t c_t * hb[j_t,:]  (4 nonzeros/iter) ----
    int nq = npad >> 2;
    float acc0=0.f,acc1=0.f,acc2=0.f,acc3=0.f,acc4=0.f,acc5=0.f,acc6=0.f,acc7=0.f;
    const unsigned short* hcol = hb + ln * 8;
    int q = 0;
    for (; q + 1 < nq; q += 2) {
        int t0 = q * 4 + wv, t1 = t0 + 4;
        int ja = s_idx[t0]; float ca = s_c[t0];
        int jb = s_idx[t1]; float cb = s_c[t1];
        uint4 ra = *(const uint4*)(hcol + (size_t)ja * DD);
        uint4 rb = *(const uint4*)(hcol + (size_t)jb * DD);
        acc0 = fmaf(ca, bflo(ra.x), acc0); acc1 = fmaf(ca, bfhi(ra.x), acc1);
        acc2 = fmaf(ca, bflo(ra.y), acc2); acc3 = fmaf(ca, bfhi(ra.y), acc3);
        acc4 = fmaf(ca, bflo(ra.z), acc4); acc5 = fmaf(ca, bfhi(ra.z), acc5);
        acc6 = fmaf(ca, bflo(ra.w), acc6); acc7 = fmaf(ca, bfhi(ra.w), acc7);
        acc0 = fmaf(cb, bflo(rb.x), acc0); acc1 = fmaf(cb, bfhi(rb.x), acc1);
        acc2 = fmaf(cb, bflo(rb.y), acc2); acc3 = fmaf(cb, bfhi(rb.y), acc3);
        acc4 = fmaf(cb, bflo(rb.z), acc4); acc5 = fmaf(cb, bfhi(rb.z), acc5);
        acc6 = fmaf(cb, bflo(rb.w), acc6); acc7 = fmaf(cb, bfhi(rb.w), acc7);
    }
    if (q < nq) {
        int t0 = q * 4 + wv;
        int ja = s_idx[t0]; float ca = s_c[t0];
        uint4 ra = *(const uint4*)(hcol + (size_t)ja * DD);
        acc0 = fmaf(ca, bflo(ra.x), acc0); acc1 = fmaf(ca, bfhi(ra.x), acc1);
        acc2 = fmaf(ca, bflo(ra.y), acc2); acc3 = fmaf(ca, bfhi(ra.y), acc3);
        acc4 = fmaf(ca, bflo(ra.z), acc4); acc5 = fmaf(ca, bfhi(ra.z), acc5);
        acc6 = fmaf(ca, bflo(ra.w), acc6); acc7 = fmaf(ca, bfhi(ra.w), acc7);
    }

    // cross-wave combine
    float4* sp = (float4*)&s_part[wv][ln * 8];
    sp[0] = make_float4(acc0, acc1, acc2, acc3);
    sp[1] = make_float4(acc4, acc5, acc6, acc7);
    __syncthreads();
    int c0 = tid * 2;
    float2 p0 = *(const float2*)&s_part[0][c0];
    float2 p1 = *(const float2*)&s_part[1][c0];
    float2 p2 = *(const float2*)&s_part[2][c0];
    float2 p3 = *(const float2*)&s_part[3][c0];
    float r0 = (p0.x + p1.x) + (p2.x + p3.x);
    float r1 = (p0.y + p1.y) + (p2.y + p3.y);
    ((float2*)(out + (size_t)row * DD))[tid] = make_float2(r0, r1);
}

extern "C" void kernel_launch(void* const* d_in, const int* in_sizes, int n_in,
                              void* d_out, int out_size, void* d_ws, size_t ws_size,
                              hipStream_t stream) {
    const float* g = (const float*)d_in[0];   // graph_info [N,N]
    const float* h = (const float*)d_in[1];   // h [N,D]
    const float* P = (const float*)d_in[2];   // P [D,H]
    float* out = (float*)d_out;               // [N,D] fp32

    // ws layout: w fp32 [N,3] at 0 (48 KB); bf16 h copy [N,D] at 64 KB (4 MB)
    float* w = (float*)d_ws;
    unsigned short* hb = (unsigned short*)((char*)d_ws + 65536);

    prep_kernel<<<(NN * 64) / 256, 256, 0, stream>>>(h, P, w, hb);
    att_agg_kernel<<<NN, 256, 0, stream>>>(g, hb, w, out);
}